// Round 1
// baseline (508.875 us; speedup 1.0000x reference)
//
#include <hip/hip_runtime.h>
#include <hip/hip_bf16.h>

typedef float f2 __attribute__((ext_vector_type(2)));
typedef float f4 __attribute__((ext_vector_type(4)));

#define N_NODES 50000
#define N_EDGES 800000
#define CH 128
#define N_GRAPHS 512

// ---------------- degree histogram ----------------
__global__ __launch_bounds__(256) void deg_hist_k(const int* __restrict__ dst,
                                                  int* __restrict__ deg) {
    int e = blockIdx.x * 256 + threadIdx.x;
    if (e < N_EDGES) atomicAdd(&deg[dst[e]], 1);
}

// ---------------- 3-step exclusive scan over 50000 ints ----------------
__global__ __launch_bounds__(1024) void scan1_k(const int* __restrict__ deg,
                                                int* __restrict__ tmp,
                                                int* __restrict__ bsum, int n) {
    __shared__ int s[1024];
    int tid = threadIdx.x;
    int gid = blockIdx.x * 1024 + tid;
    int v = (gid < n) ? deg[gid] : 0;
    s[tid] = v;
    __syncthreads();
    for (int off = 1; off < 1024; off <<= 1) {
        int t = (tid >= off) ? s[tid - off] : 0;
        __syncthreads();
        s[tid] += t;
        __syncthreads();
    }
    if (gid < n) tmp[gid] = s[tid];
    if (tid == 1023) bsum[blockIdx.x] = s[tid];
}

__global__ void scan2_k(int* __restrict__ bsum, int nb) {
    int lane = threadIdx.x;  // one wave of 64
    int v = (lane < nb) ? bsum[lane] : 0;
    for (int off = 1; off < 64; off <<= 1) {
        int t = __shfl_up(v, off);
        if (lane >= off) v += t;
    }
    if (lane < nb) bsum[lane] = v;
}

// writes row_ptr (exclusive), cursor copy, and dinv = rsqrt(deg+1)
__global__ __launch_bounds__(1024) void scan3_k(const int* __restrict__ tmp,
                                                const int* __restrict__ bsum,
                                                const int* __restrict__ deg,
                                                int* __restrict__ rowp,
                                                int* __restrict__ cursor,
                                                float* __restrict__ dinv, int n) {
    int gid = blockIdx.x * 1024 + threadIdx.x;
    if (gid >= n) return;
    int off = blockIdx.x ? bsum[blockIdx.x - 1] : 0;
    int incl = tmp[gid] + off;
    rowp[gid + 1] = incl;
    cursor[gid] = incl - deg[gid];
    dinv[gid] = rsqrtf((float)deg[gid] + 1.0f);  // +1 for self-loop
    if (gid == 0) rowp[0] = 0;
}

// ---------------- CSR fill (src ids bucketed by dst) ----------------
__global__ __launch_bounds__(256) void csr_fill_k(const int* __restrict__ src,
                                                  const int* __restrict__ dst,
                                                  int* __restrict__ cursor,
                                                  int* __restrict__ csr) {
    int e = blockIdx.x * 256 + threadIdx.x;
    if (e < N_EDGES) {
        int d = dst[e];
        int pos = atomicAdd(&cursor[d], 1);
        csr[pos] = src[e];
    }
}

// ---------------- GEMM: C[M,128] = A[M,128] @ W[128,128] ----------------
// 64x64 tile per block, 16x16 threads, 4x4 microtile, LDS-staged, padded.
__global__ __launch_bounds__(256) void gemm_k(const float* __restrict__ A,
                                              const float* __restrict__ W,
                                              float* __restrict__ C, int M) {
    __shared__ float sA[64][132];   // padded: +4 keeps 16B align, spreads banks
    __shared__ float sW[128][68];
    int tid = threadIdx.x;
    int row0 = blockIdx.x * 64;
    int col0 = blockIdx.y * 64;

    // stage A tile (64 rows x 128 k)
    #pragma unroll
    for (int rep = 0; rep < 8; ++rep) {
        int idx = rep * 256 + tid;       // 0..2047
        int r = idx >> 5, k4 = idx & 31;
        f4 v = {0.f, 0.f, 0.f, 0.f};
        int row = row0 + r;
        if (row < M) v = *(const f4*)&A[row * 128 + k4 * 4];
        *(f4*)&sA[r][k4 * 4] = v;
    }
    // stage W tile (128 k x 64 cols)
    #pragma unroll
    for (int rep = 0; rep < 8; ++rep) {
        int idx = rep * 256 + tid;       // 0..2047
        int k = idx >> 4, c4 = idx & 15;
        f4 v = *(const f4*)&W[k * 128 + col0 + c4 * 4];
        *(f4*)&sW[k][c4 * 4] = v;
    }
    __syncthreads();

    int tx = tid & 15, ty = tid >> 4;
    float acc[4][4] = {};
    for (int k = 0; k < 128; k += 4) {
        f4 a[4], b[4];
        #pragma unroll
        for (int i = 0; i < 4; ++i) a[i] = *(const f4*)&sA[ty * 4 + i][k];
        #pragma unroll
        for (int kk = 0; kk < 4; ++kk) b[kk] = *(const f4*)&sW[k + kk][tx * 4];
        #pragma unroll
        for (int i = 0; i < 4; ++i)
            #pragma unroll
            for (int j = 0; j < 4; ++j)
                acc[i][j] += a[i][0] * b[0][j] + a[i][1] * b[1][j] +
                             a[i][2] * b[2][j] + a[i][3] * b[3][j];
    }
    #pragma unroll
    for (int i = 0; i < 4; ++i) {
        int row = row0 + ty * 4 + i;
        if (row < M) {
            f4 v = {acc[i][0], acc[i][1], acc[i][2], acc[i][3]};
            *(f4*)&C[row * 128 + col0 + tx * 4] = v;
        }
    }
}

// ---------------- layer-1 aggregate: one wave per node ----------------
__global__ __launch_bounds__(256) void gather1_k(const float* __restrict__ xw,
                                                 const float* __restrict__ dinv,
                                                 const int* __restrict__ rowp,
                                                 const int* __restrict__ csr,
                                                 const float* __restrict__ bias,
                                                 float* __restrict__ h) {
    int node = blockIdx.x * 4 + (threadIdx.x >> 6);
    if (node >= N_NODES) return;
    int lane = threadIdx.x & 63;
    int beg = rowp[node], end = rowp[node + 1];
    f2 acc = {0.f, 0.f};
    for (int j = beg; j < end; ++j) {
        int s = csr[j];
        float w = dinv[s];
        f2 v = *(const f2*)&xw[s * 128 + lane * 2];
        acc += v * w;
    }
    float dn = dinv[node];
    f2 selfv = *(const f2*)&xw[node * 128 + lane * 2];
    f2 bb = *(const f2*)&bias[lane * 2];
    f2 o = acc * dn + selfv * (dn * dn) + bb;
    o[0] = fmaxf(o[0], 0.f);
    o[1] = fmaxf(o[1], 0.f);
    *(f2*)&h[node * 128 + lane * 2] = o;
}

// ------- layer-2 aggregate fused with mean-pool dot(Wfc): no h2 write -------
__global__ __launch_bounds__(256) void gather2_pool_k(const float* __restrict__ xw,
                                                      const float* __restrict__ dinv,
                                                      const int* __restrict__ rowp,
                                                      const int* __restrict__ csr,
                                                      const float* __restrict__ bias,
                                                      const int* __restrict__ batch,
                                                      const float* __restrict__ Wfc,
                                                      float* __restrict__ pool,
                                                      float* __restrict__ cnt) {
    int node = blockIdx.x * 4 + (threadIdx.x >> 6);
    if (node >= N_NODES) return;
    int lane = threadIdx.x & 63;
    int beg = rowp[node], end = rowp[node + 1];
    f2 acc = {0.f, 0.f};
    for (int j = beg; j < end; ++j) {
        int s = csr[j];
        float w = dinv[s];
        f2 v = *(const f2*)&xw[s * 128 + lane * 2];
        acc += v * w;
    }
    float dn = dinv[node];
    f2 selfv = *(const f2*)&xw[node * 128 + lane * 2];
    f2 bb = *(const f2*)&bias[lane * 2];
    f2 o = acc * dn + selfv * (dn * dn) + bb;
    o[0] = fmaxf(o[0], 0.f);
    o[1] = fmaxf(o[1], 0.f);
    f2 wf = *(const f2*)&Wfc[lane * 2];
    float p = o[0] * wf[0] + o[1] * wf[1];
    #pragma unroll
    for (int off = 32; off > 0; off >>= 1) p += __shfl_down(p, off);
    if (lane == 0) {
        int g = batch[node];
        atomicAdd(&pool[g], p);
        atomicAdd(&cnt[g], 1.0f);
    }
}

__global__ void finalize_k(const float* __restrict__ pool,
                           const float* __restrict__ cnt,
                           const float* __restrict__ bfc,
                           float* __restrict__ out) {
    int g = blockIdx.x * blockDim.x + threadIdx.x;
    if (g < N_GRAPHS) out[g] = pool[g] / fmaxf(cnt[g], 1.0f) + bfc[0];
}

extern "C" void kernel_launch(void* const* d_in, const int* in_sizes, int n_in,
                              void* d_out, int out_size, void* d_ws, size_t ws_size,
                              hipStream_t stream) {
    const float* x    = (const float*)d_in[0];
    const int*   ei   = (const int*)d_in[1];   // [2, E] flat, int32
    const int*   batch= (const int*)d_in[2];
    const float* W1   = (const float*)d_in[3];
    const float* b1   = (const float*)d_in[4];
    const float* W2   = (const float*)d_in[5];
    const float* b2   = (const float*)d_in[6];
    const float* Wfc  = (const float*)d_in[7];
    const float* bfc  = (const float*)d_in[8];
    float* out = (float*)d_out;

    const int* src = ei;
    const int* dst = ei + N_EDGES;

    // workspace carve-up (all 16B-aligned)
    char* w = (char*)d_ws;
    float* dinv   = (float*)w; w += 50048 * 4;
    int*   deg    = (int*)w;   w += 50048 * 4;
    int*   rowp   = (int*)w;   w += 50052 * 4;   // 50001 ints
    int*   cursor = (int*)w;   w += 50048 * 4;
    int*   stmp   = (int*)w;   w += 50048 * 4;
    int*   bsum   = (int*)w;   w += 256 * 4;
    int*   csr    = (int*)w;   w += N_EDGES * 4;
    float* xw     = (float*)w; w += (size_t)N_NODES * 128 * 4;
    float* h1     = (float*)w; w += (size_t)N_NODES * 128 * 4;
    float* pool   = (float*)w; w += 512 * 4;
    float* cnt    = (float*)w; w += 512 * 4;

    hipMemsetAsync(deg, 0, N_NODES * sizeof(int), stream);
    hipMemsetAsync(pool, 0, 2 * 512 * sizeof(float), stream);  // pool + cnt contiguous

    int eb = (N_EDGES + 255) / 256;
    deg_hist_k<<<eb, 256, 0, stream>>>(dst, deg);

    int nb = (N_NODES + 1023) / 1024;   // 49
    scan1_k<<<nb, 1024, 0, stream>>>(deg, stmp, bsum, N_NODES);
    scan2_k<<<1, 64, 0, stream>>>(bsum, nb);
    scan3_k<<<nb, 1024, 0, stream>>>(stmp, bsum, deg, rowp, cursor, dinv, N_NODES);

    csr_fill_k<<<eb, 256, 0, stream>>>(src, dst, cursor, csr);

    dim3 ggrid((N_NODES + 63) / 64, 2);
    gemm_k<<<ggrid, 256, 0, stream>>>(x, W1, xw, N_NODES);

    int gb = (N_NODES + 3) / 4;   // 4 waves (nodes) per 256-thread block
    gather1_k<<<gb, 256, 0, stream>>>(xw, dinv, rowp, csr, b1, h1);

    gemm_k<<<ggrid, 256, 0, stream>>>(h1, W2, xw, N_NODES);

    gather2_pool_k<<<gb, 256, 0, stream>>>(xw, dinv, rowp, csr, b2, batch, Wfc,
                                           pool, cnt);

    finalize_k<<<2, 256, 0, stream>>>(pool, cnt, bfc, out);
}

// Round 2
// 495.926 us; speedup vs baseline: 1.0261x; 1.0261x over previous
//
#include <hip/hip_runtime.h>
#include <hip/hip_bf16.h>

typedef float f2 __attribute__((ext_vector_type(2)));
typedef float f4 __attribute__((ext_vector_type(4)));
typedef _Float16 hf;
typedef hf hf2 __attribute__((ext_vector_type(2)));
typedef hf hf4 __attribute__((ext_vector_type(4)));

#define N_NODES 50000
#define N_EDGES 800000
#define CH 128
#define N_GRAPHS 512

// ---------------- degree histogram ----------------
__global__ __launch_bounds__(256) void deg_hist_k(const int* __restrict__ dst,
                                                  int* __restrict__ deg) {
    int e = blockIdx.x * 256 + threadIdx.x;
    if (e < N_EDGES) atomicAdd(&deg[dst[e]], 1);
}

// ---------------- 3-step exclusive scan over 50000 ints ----------------
__global__ __launch_bounds__(1024) void scan1_k(const int* __restrict__ deg,
                                                int* __restrict__ tmp,
                                                int* __restrict__ bsum, int n) {
    __shared__ int s[1024];
    int tid = threadIdx.x;
    int gid = blockIdx.x * 1024 + tid;
    int v = (gid < n) ? deg[gid] : 0;
    s[tid] = v;
    __syncthreads();
    for (int off = 1; off < 1024; off <<= 1) {
        int t = (tid >= off) ? s[tid - off] : 0;
        __syncthreads();
        s[tid] += t;
        __syncthreads();
    }
    if (gid < n) tmp[gid] = s[tid];
    if (tid == 1023) bsum[blockIdx.x] = s[tid];
}

__global__ void scan2_k(int* __restrict__ bsum, int nb) {
    int lane = threadIdx.x;  // one wave of 64
    int v = (lane < nb) ? bsum[lane] : 0;
    for (int off = 1; off < 64; off <<= 1) {
        int t = __shfl_up(v, off);
        if (lane >= off) v += t;
    }
    if (lane < nb) bsum[lane] = v;
}

// writes row_ptr (exclusive), cursor copy, and dinv = rsqrt(deg+1)
__global__ __launch_bounds__(1024) void scan3_k(const int* __restrict__ tmp,
                                                const int* __restrict__ bsum,
                                                const int* __restrict__ deg,
                                                int* __restrict__ rowp,
                                                int* __restrict__ cursor,
                                                float* __restrict__ dinv, int n) {
    int gid = blockIdx.x * 1024 + threadIdx.x;
    if (gid >= n) return;
    int off = blockIdx.x ? bsum[blockIdx.x - 1] : 0;
    int incl = tmp[gid] + off;
    rowp[gid + 1] = incl;
    cursor[gid] = incl - deg[gid];
    dinv[gid] = rsqrtf((float)deg[gid] + 1.0f);  // +1 for self-loop
    if (gid == 0) rowp[0] = 0;
}

// ---------------- CSR fill (src ids bucketed by dst) ----------------
__global__ __launch_bounds__(256) void csr_fill_k(const int* __restrict__ src,
                                                  const int* __restrict__ dst,
                                                  int* __restrict__ cursor,
                                                  int* __restrict__ csr) {
    int e = blockIdx.x * 256 + threadIdx.x;
    if (e < N_EDGES) {
        int d = dst[e];
        int pos = atomicAdd(&cursor[d], 1);
        csr[pos] = src[e];
    }
}

// ------- GEMM: out[M,128] = (A[M,128] @ W[128,128]) * dinv[row], fp16 out ----
// 64x64 tile per block, 16x16 threads, 4x4 microtile, LDS-staged, padded.
// TA = float (layer 1, reads x) or _Float16 (layer 2, reads h1).
template <typename TA>
__global__ __launch_bounds__(256) void gemm_scaled_k(const TA* __restrict__ A,
                                                     const float* __restrict__ W,
                                                     const float* __restrict__ dinv,
                                                     hf* __restrict__ out, int M) {
    __shared__ float sA[64][132];   // padded
    __shared__ float sW[128][68];
    int tid = threadIdx.x;
    int row0 = blockIdx.x * 64;
    int col0 = blockIdx.y * 64;

    // stage A tile (64 rows x 128 k), convert to fp32 in LDS
    #pragma unroll
    for (int rep = 0; rep < 8; ++rep) {
        int idx = rep * 256 + tid;       // 0..2047, 4 ch each
        int r = idx >> 5, k4 = idx & 31;
        f4 vf = {0.f, 0.f, 0.f, 0.f};
        int row = row0 + r;
        if (row < M) {
            if constexpr (sizeof(TA) == 4) {
                vf = *(const f4*)&A[row * 128 + k4 * 4];
            } else {
                hf4 v = *(const hf4*)&A[row * 128 + k4 * 4];
                vf = f4{(float)v[0], (float)v[1], (float)v[2], (float)v[3]};
            }
        }
        *(f4*)&sA[r][k4 * 4] = vf;
    }
    // stage W tile (128 k x 64 cols)
    #pragma unroll
    for (int rep = 0; rep < 8; ++rep) {
        int idx = rep * 256 + tid;       // 0..2047
        int k = idx >> 4, c4 = idx & 15;
        f4 v = *(const f4*)&W[k * 128 + col0 + c4 * 4];
        *(f4*)&sW[k][c4 * 4] = v;
    }
    __syncthreads();

    int tx = tid & 15, ty = tid >> 4;
    float acc[4][4] = {};
    for (int k = 0; k < 128; k += 4) {
        f4 a[4], b[4];
        #pragma unroll
        for (int i = 0; i < 4; ++i) a[i] = *(const f4*)&sA[ty * 4 + i][k];
        #pragma unroll
        for (int kk = 0; kk < 4; ++kk) b[kk] = *(const f4*)&sW[k + kk][tx * 4];
        #pragma unroll
        for (int i = 0; i < 4; ++i)
            #pragma unroll
            for (int j = 0; j < 4; ++j)
                acc[i][j] += a[i][0] * b[0][j] + a[i][1] * b[1][j] +
                             a[i][2] * b[2][j] + a[i][3] * b[3][j];
    }
    #pragma unroll
    for (int i = 0; i < 4; ++i) {
        int row = row0 + ty * 4 + i;
        if (row < M) {
            float dv = dinv[row];
            hf4 o = {(hf)(acc[i][0] * dv), (hf)(acc[i][1] * dv),
                     (hf)(acc[i][2] * dv), (hf)(acc[i][3] * dv)};
            *(hf4*)&out[row * 128 + col0 + tx * 4] = o;
        }
    }
}

// ---------------- layer-1 aggregate: one wave per node ----------------
// xws rows are pre-scaled by dinv[src]; self-loop = own row. Output fp16.
__global__ __launch_bounds__(256) void gather1_k(const hf* __restrict__ xws,
                                                 const float* __restrict__ dinv,
                                                 const int* __restrict__ rowp,
                                                 const int* __restrict__ csr,
                                                 const float* __restrict__ bias,
                                                 hf* __restrict__ h) {
    int node = blockIdx.x * 4 + (threadIdx.x >> 6);
    if (node >= N_NODES) return;
    int lane = threadIdx.x & 63;
    int beg = rowp[node], end = rowp[node + 1];
    const hf2* base = (const hf2*)xws;
    float a0 = 0.f, a1 = 0.f;
    for (int j = beg; j < end; ++j) {
        int s = csr[j];
        hf2 v = base[s * 64 + lane];
        a0 += (float)v[0];
        a1 += (float)v[1];
    }
    hf2 sv = base[node * 64 + lane];      // self loop
    a0 += (float)sv[0];
    a1 += (float)sv[1];
    float dn = dinv[node];
    f2 bb = *(const f2*)&bias[lane * 2];
    float o0 = fmaxf(a0 * dn + bb[0], 0.f);
    float o1 = fmaxf(a1 * dn + bb[1], 0.f);
    ((hf2*)h)[node * 64 + lane] = hf2{(hf)o0, (hf)o1};
}

// ------- layer-2 aggregate fused with mean-pool dot(Wfc): no h2 write -------
__global__ __launch_bounds__(256) void gather2_pool_k(const hf* __restrict__ xws,
                                                      const float* __restrict__ dinv,
                                                      const int* __restrict__ rowp,
                                                      const int* __restrict__ csr,
                                                      const float* __restrict__ bias,
                                                      const int* __restrict__ batch,
                                                      const float* __restrict__ Wfc,
                                                      float* __restrict__ pool,
                                                      float* __restrict__ cnt) {
    int node = blockIdx.x * 4 + (threadIdx.x >> 6);
    if (node >= N_NODES) return;
    int lane = threadIdx.x & 63;
    int beg = rowp[node], end = rowp[node + 1];
    const hf2* base = (const hf2*)xws;
    float a0 = 0.f, a1 = 0.f;
    for (int j = beg; j < end; ++j) {
        int s = csr[j];
        hf2 v = base[s * 64 + lane];
        a0 += (float)v[0];
        a1 += (float)v[1];
    }
    hf2 sv = base[node * 64 + lane];      // self loop
    a0 += (float)sv[0];
    a1 += (float)sv[1];
    float dn = dinv[node];
    f2 bb = *(const f2*)&bias[lane * 2];
    float o0 = fmaxf(a0 * dn + bb[0], 0.f);
    float o1 = fmaxf(a1 * dn + bb[1], 0.f);
    f2 wf = *(const f2*)&Wfc[lane * 2];
    float p = o0 * wf[0] + o1 * wf[1];
    #pragma unroll
    for (int off = 32; off > 0; off >>= 1) p += __shfl_down(p, off);
    if (lane == 0) {
        int g = batch[node];
        atomicAdd(&pool[g], p);
        atomicAdd(&cnt[g], 1.0f);
    }
}

__global__ void finalize_k(const float* __restrict__ pool,
                           const float* __restrict__ cnt,
                           const float* __restrict__ bfc,
                           float* __restrict__ out) {
    int g = blockIdx.x * blockDim.x + threadIdx.x;
    if (g < N_GRAPHS) out[g] = pool[g] / fmaxf(cnt[g], 1.0f) + bfc[0];
}

extern "C" void kernel_launch(void* const* d_in, const int* in_sizes, int n_in,
                              void* d_out, int out_size, void* d_ws, size_t ws_size,
                              hipStream_t stream) {
    const float* x    = (const float*)d_in[0];
    const int*   ei   = (const int*)d_in[1];   // [2, E] flat, int32
    const int*   batch= (const int*)d_in[2];
    const float* W1   = (const float*)d_in[3];
    const float* b1   = (const float*)d_in[4];
    const float* W2   = (const float*)d_in[5];
    const float* b2   = (const float*)d_in[6];
    const float* Wfc  = (const float*)d_in[7];
    const float* bfc  = (const float*)d_in[8];
    float* out = (float*)d_out;

    const int* src = ei;
    const int* dst = ei + N_EDGES;

    // workspace carve-up (all 16B-aligned)
    char* w = (char*)d_ws;
    float* dinv   = (float*)w; w += 50048 * 4;
    int*   deg    = (int*)w;   w += 50048 * 4;
    int*   rowp   = (int*)w;   w += 50052 * 4;   // 50001 ints
    int*   cursor = (int*)w;   w += 50048 * 4;
    int*   stmp   = (int*)w;   w += 50048 * 4;
    int*   bsum   = (int*)w;   w += 256 * 4;
    int*   csr    = (int*)w;   w += N_EDGES * 4;
    hf*    xws1   = (hf*)w;    w += (size_t)N_NODES * 128 * 2;
    hf*    h1     = (hf*)w;    w += (size_t)N_NODES * 128 * 2;
    hf*    xws2   = (hf*)w;    w += (size_t)N_NODES * 128 * 2;
    float* pool   = (float*)w; w += 512 * 4;
    float* cnt    = (float*)w; w += 512 * 4;

    hipMemsetAsync(deg, 0, N_NODES * sizeof(int), stream);
    hipMemsetAsync(pool, 0, 2 * 512 * sizeof(float), stream);  // pool + cnt contiguous

    int eb = (N_EDGES + 255) / 256;
    deg_hist_k<<<eb, 256, 0, stream>>>(dst, deg);

    int nb = (N_NODES + 1023) / 1024;   // 49
    scan1_k<<<nb, 1024, 0, stream>>>(deg, stmp, bsum, N_NODES);
    scan2_k<<<1, 64, 0, stream>>>(bsum, nb);
    scan3_k<<<nb, 1024, 0, stream>>>(stmp, bsum, deg, rowp, cursor, dinv, N_NODES);

    csr_fill_k<<<eb, 256, 0, stream>>>(src, dst, cursor, csr);

    dim3 ggrid((N_NODES + 63) / 64, 2);
    gemm_scaled_k<float><<<ggrid, 256, 0, stream>>>(x, W1, dinv, xws1, N_NODES);

    int gb = (N_NODES + 3) / 4;   // 4 waves (nodes) per 256-thread block
    gather1_k<<<gb, 256, 0, stream>>>(xws1, dinv, rowp, csr, b1, h1);

    gemm_scaled_k<hf><<<ggrid, 256, 0, stream>>>(h1, W2, dinv, xws2, N_NODES);

    gather2_pool_k<<<gb, 256, 0, stream>>>(xws2, dinv, rowp, csr, b2, batch, Wfc,
                                           pool, cnt);

    finalize_k<<<2, 256, 0, stream>>>(pool, cnt, bfc, out);
}

// Round 3
// 435.003 us; speedup vs baseline: 1.1698x; 1.1401x over previous
//
#include <hip/hip_runtime.h>
#include <hip/hip_bf16.h>

typedef float f2 __attribute__((ext_vector_type(2)));
typedef float f4 __attribute__((ext_vector_type(4)));
typedef _Float16 hf;
typedef hf hf2 __attribute__((ext_vector_type(2)));
typedef hf hf4 __attribute__((ext_vector_type(4)));

#define N_NODES 50000
#define N_EDGES 800000
#define CH 128
#define N_GRAPHS 512

// ---------------- degree histogram ----------------
__global__ __launch_bounds__(256) void deg_hist_k(const int* __restrict__ dst,
                                                  int* __restrict__ deg) {
    int e = blockIdx.x * 256 + threadIdx.x;
    if (e < N_EDGES) atomicAdd(&deg[dst[e]], 1);
}

// ---------------- 3-step exclusive scan over 50000 ints ----------------
__global__ __launch_bounds__(1024) void scan1_k(const int* __restrict__ deg,
                                                int* __restrict__ tmp,
                                                int* __restrict__ bsum, int n) {
    __shared__ int s[1024];
    int tid = threadIdx.x;
    int gid = blockIdx.x * 1024 + tid;
    int v = (gid < n) ? deg[gid] : 0;
    s[tid] = v;
    __syncthreads();
    for (int off = 1; off < 1024; off <<= 1) {
        int t = (tid >= off) ? s[tid - off] : 0;
        __syncthreads();
        s[tid] += t;
        __syncthreads();
    }
    if (gid < n) tmp[gid] = s[tid];
    if (tid == 1023) bsum[blockIdx.x] = s[tid];
}

__global__ void scan2_k(int* __restrict__ bsum, int nb) {
    int lane = threadIdx.x;  // one wave of 64
    int v = (lane < nb) ? bsum[lane] : 0;
    for (int off = 1; off < 64; off <<= 1) {
        int t = __shfl_up(v, off);
        if (lane >= off) v += t;
    }
    if (lane < nb) bsum[lane] = v;
}

// writes row_ptr (exclusive), cursor copy, and dinv = rsqrt(deg+1)
__global__ __launch_bounds__(1024) void scan3_k(const int* __restrict__ tmp,
                                                const int* __restrict__ bsum,
                                                const int* __restrict__ deg,
                                                int* __restrict__ rowp,
                                                int* __restrict__ cursor,
                                                float* __restrict__ dinv, int n) {
    int gid = blockIdx.x * 1024 + threadIdx.x;
    if (gid >= n) return;
    int off = blockIdx.x ? bsum[blockIdx.x - 1] : 0;
    int incl = tmp[gid] + off;
    rowp[gid + 1] = incl;
    cursor[gid] = incl - deg[gid];
    dinv[gid] = rsqrtf((float)deg[gid] + 1.0f);  // +1 for self-loop
    if (gid == 0) rowp[0] = 0;
}

// ---------------- CSR fill (src ids bucketed by dst) ----------------
__global__ __launch_bounds__(256) void csr_fill_k(const int* __restrict__ src,
                                                  const int* __restrict__ dst,
                                                  int* __restrict__ cursor,
                                                  int* __restrict__ csr) {
    int e = blockIdx.x * 256 + threadIdx.x;
    if (e < N_EDGES) {
        int d = dst[e];
        int pos = atomicAdd(&cursor[d], 1);
        csr[pos] = src[e];
    }
}

// ------- GEMM: out[M,128] = (A[M,128] @ W[128,128]) * dinv[row], fp16 out ----
template <typename TA>
__global__ __launch_bounds__(256) void gemm_scaled_k(const TA* __restrict__ A,
                                                     const float* __restrict__ W,
                                                     const float* __restrict__ dinv,
                                                     hf* __restrict__ out, int M) {
    __shared__ float sA[64][132];   // padded
    __shared__ float sW[128][68];
    int tid = threadIdx.x;
    int row0 = blockIdx.x * 64;
    int col0 = blockIdx.y * 64;

    #pragma unroll
    for (int rep = 0; rep < 8; ++rep) {
        int idx = rep * 256 + tid;       // 0..2047, 4 ch each
        int r = idx >> 5, k4 = idx & 31;
        f4 vf = {0.f, 0.f, 0.f, 0.f};
        int row = row0 + r;
        if (row < M) {
            if constexpr (sizeof(TA) == 4) {
                vf = *(const f4*)&A[row * 128 + k4 * 4];
            } else {
                hf4 v = *(const hf4*)&A[row * 128 + k4 * 4];
                vf = f4{(float)v[0], (float)v[1], (float)v[2], (float)v[3]};
            }
        }
        *(f4*)&sA[r][k4 * 4] = vf;
    }
    #pragma unroll
    for (int rep = 0; rep < 8; ++rep) {
        int idx = rep * 256 + tid;       // 0..2047
        int k = idx >> 4, c4 = idx & 15;
        f4 v = *(const f4*)&W[k * 128 + col0 + c4 * 4];
        *(f4*)&sW[k][c4 * 4] = v;
    }
    __syncthreads();

    int tx = tid & 15, ty = tid >> 4;
    float acc[4][4] = {};
    for (int k = 0; k < 128; k += 4) {
        f4 a[4], b[4];
        #pragma unroll
        for (int i = 0; i < 4; ++i) a[i] = *(const f4*)&sA[ty * 4 + i][k];
        #pragma unroll
        for (int kk = 0; kk < 4; ++kk) b[kk] = *(const f4*)&sW[k + kk][tx * 4];
        #pragma unroll
        for (int i = 0; i < 4; ++i)
            #pragma unroll
            for (int j = 0; j < 4; ++j)
                acc[i][j] += a[i][0] * b[0][j] + a[i][1] * b[1][j] +
                             a[i][2] * b[2][j] + a[i][3] * b[3][j];
    }
    #pragma unroll
    for (int i = 0; i < 4; ++i) {
        int row = row0 + ty * 4 + i;
        if (row < M) {
            float dv = dinv[row];
            hf4 o = {(hf)(acc[i][0] * dv), (hf)(acc[i][1] * dv),
                     (hf)(acc[i][2] * dv), (hf)(acc[i][3] * dv)};
            *(hf4*)&out[row * 128 + col0 + tx * 4] = o;
        }
    }
}

// ---------------- ILP gather core ----------------
// One wave per node. Edge ids (incl. self at slot 0) prefetched in ONE
// coalesced load into registers, broadcast via shfl. Row = 256B = 32 lanes
// x hf4: half-wave 0 takes even edges, half-wave 1 odd edges; unroll x4 ->
// 8 independent row loads in flight. Combine halves with one shfl(lane^32).
// Returns per-lane f4: channels hl*4..hl*4+3 of dinv[node]*(sum)+... raw sum.
__device__ __forceinline__ f4 gather_core(const hf4* __restrict__ rows,
                                          const int* __restrict__ rowp,
                                          const int* __restrict__ csr,
                                          int node, int lane) {
    int half = lane >> 5;        // 0: even edges, 1: odd edges
    int hl = lane & 31;          // 8B chunk within 256B row
    int beg = rowp[node], end = rowp[node + 1];
    int cnt = end - beg + 1;     // + self
    // prefetch: slot 0 = self, slots 1.. = csr[beg..]
    int myE;
    if (lane == 0) myE = node;
    else {
        int j = beg + lane - 1;
        myE = (j < end) ? csr[j] : 0;
    }
    f4 acc = {0.f, 0.f, 0.f, 0.f};
    int pre = cnt < 64 ? cnt : 64;
    int e = 0;
    for (; e + 8 <= pre; e += 8) {
        int s0 = __shfl(myE, e + half);
        int s1 = __shfl(myE, e + 2 + half);
        int s2 = __shfl(myE, e + 4 + half);
        int s3 = __shfl(myE, e + 6 + half);
        hf4 v0 = rows[s0 * 32 + hl];
        hf4 v1 = rows[s1 * 32 + hl];
        hf4 v2 = rows[s2 * 32 + hl];
        hf4 v3 = rows[s3 * 32 + hl];
        #pragma unroll
        for (int k = 0; k < 4; ++k)
            acc[k] += (float)v0[k] + (float)v1[k] + (float)v2[k] + (float)v3[k];
    }
    for (; e + 2 <= pre; e += 2) {
        int s0 = __shfl(myE, e + half);
        hf4 v0 = rows[s0 * 32 + hl];
        #pragma unroll
        for (int k = 0; k < 4; ++k) acc[k] += (float)v0[k];
    }
    if (e < pre && half == 0) {      // odd leftover: half 0 only
        int s0 = __shfl(myE, e);
        hf4 v0 = rows[s0 * 32 + hl];
        #pragma unroll
        for (int k = 0; k < 4; ++k) acc[k] += (float)v0[k];
    }
    // overflow tail (cnt > 64): csr[beg+63 .. end-1], uniform loads
    for (int j = beg + 63; j < end; ++j) {
        int s = csr[j];
        hf4 v = rows[s * 32 + hl];
        if (half == 0) {
            #pragma unroll
            for (int k = 0; k < 4; ++k) acc[k] += (float)v[k];
        }
    }
    // combine halves
    #pragma unroll
    for (int k = 0; k < 4; ++k) acc[k] += __shfl(acc[k], lane ^ 32);
    return acc;
}

// ---------------- layer-1 aggregate ----------------
__global__ __launch_bounds__(256) void gather1_k(const hf* __restrict__ xws,
                                                 const float* __restrict__ dinv,
                                                 const int* __restrict__ rowp,
                                                 const int* __restrict__ csr,
                                                 const float* __restrict__ bias,
                                                 hf* __restrict__ h) {
    int node = blockIdx.x * 4 + (threadIdx.x >> 6);
    if (node >= N_NODES) return;
    int lane = threadIdx.x & 63;
    f4 acc = gather_core((const hf4*)xws, rowp, csr, node, lane);
    if (lane < 32) {
        int hl = lane;
        float dn = dinv[node];
        f4 bb = *(const f4*)&bias[hl * 4];
        hf4 o;
        #pragma unroll
        for (int k = 0; k < 4; ++k)
            o[k] = (hf)fmaxf(acc[k] * dn + bb[k], 0.f);
        ((hf4*)h)[node * 32 + hl] = o;
    }
}

// ------- layer-2 aggregate fused with mean-pool dot(Wfc) -------
__global__ __launch_bounds__(256) void gather2_pool_k(const hf* __restrict__ xws,
                                                      const float* __restrict__ dinv,
                                                      const int* __restrict__ rowp,
                                                      const int* __restrict__ csr,
                                                      const float* __restrict__ bias,
                                                      const int* __restrict__ batch,
                                                      const float* __restrict__ Wfc,
                                                      float* __restrict__ pool,
                                                      float* __restrict__ cnt) {
    int node = blockIdx.x * 4 + (threadIdx.x >> 6);
    if (node >= N_NODES) return;
    int lane = threadIdx.x & 63;
    f4 acc = gather_core((const hf4*)xws, rowp, csr, node, lane);
    int hl = lane & 31;
    float dn = dinv[node];
    f4 bb = *(const f4*)&bias[hl * 4];
    f4 wf = *(const f4*)&Wfc[hl * 4];
    float p = 0.f;
    #pragma unroll
    for (int k = 0; k < 4; ++k)
        p += fmaxf(acc[k] * dn + bb[k], 0.f) * wf[k];
    // reduce across lanes 0..31 (half 1 holds duplicate values; harmless)
    #pragma unroll
    for (int off = 16; off > 0; off >>= 1) p += __shfl_xor(p, off);
    if (lane == 0) {
        int g = batch[node];
        atomicAdd(&pool[g], p);
        atomicAdd(&cnt[g], 1.0f);
    }
}

__global__ void finalize_k(const float* __restrict__ pool,
                           const float* __restrict__ cnt,
                           const float* __restrict__ bfc,
                           float* __restrict__ out) {
    int g = blockIdx.x * blockDim.x + threadIdx.x;
    if (g < N_GRAPHS) out[g] = pool[g] / fmaxf(cnt[g], 1.0f) + bfc[0];
}

extern "C" void kernel_launch(void* const* d_in, const int* in_sizes, int n_in,
                              void* d_out, int out_size, void* d_ws, size_t ws_size,
                              hipStream_t stream) {
    const float* x    = (const float*)d_in[0];
    const int*   ei   = (const int*)d_in[1];   // [2, E] flat, int32
    const int*   batch= (const int*)d_in[2];
    const float* W1   = (const float*)d_in[3];
    const float* b1   = (const float*)d_in[4];
    const float* W2   = (const float*)d_in[5];
    const float* b2   = (const float*)d_in[6];
    const float* Wfc  = (const float*)d_in[7];
    const float* bfc  = (const float*)d_in[8];
    float* out = (float*)d_out;

    const int* src = ei;
    const int* dst = ei + N_EDGES;

    // workspace carve-up (all 16B-aligned)
    char* w = (char*)d_ws;
    float* dinv   = (float*)w; w += 50048 * 4;
    int*   deg    = (int*)w;   w += 50048 * 4;
    int*   rowp   = (int*)w;   w += 50052 * 4;   // 50001 ints
    int*   cursor = (int*)w;   w += 50048 * 4;
    int*   stmp   = (int*)w;   w += 50048 * 4;
    int*   bsum   = (int*)w;   w += 256 * 4;
    int*   csr    = (int*)w;   w += N_EDGES * 4;
    hf*    xws1   = (hf*)w;    w += (size_t)N_NODES * 128 * 2;
    hf*    h1     = (hf*)w;    w += (size_t)N_NODES * 128 * 2;
    hf*    xws2   = (hf*)w;    w += (size_t)N_NODES * 128 * 2;
    float* pool   = (float*)w; w += 512 * 4;
    float* cnt    = (float*)w; w += 512 * 4;

    hipMemsetAsync(deg, 0, N_NODES * sizeof(int), stream);
    hipMemsetAsync(pool, 0, 2 * 512 * sizeof(float), stream);  // pool + cnt

    int eb = (N_EDGES + 255) / 256;
    deg_hist_k<<<eb, 256, 0, stream>>>(dst, deg);

    int nb = (N_NODES + 1023) / 1024;   // 49
    scan1_k<<<nb, 1024, 0, stream>>>(deg, stmp, bsum, N_NODES);
    scan2_k<<<1, 64, 0, stream>>>(bsum, nb);
    scan3_k<<<nb, 1024, 0, stream>>>(stmp, bsum, deg, rowp, cursor, dinv, N_NODES);

    csr_fill_k<<<eb, 256, 0, stream>>>(src, dst, cursor, csr);

    dim3 ggrid((N_NODES + 63) / 64, 2);
    gemm_scaled_k<float><<<ggrid, 256, 0, stream>>>(x, W1, dinv, xws1, N_NODES);

    int gb = (N_NODES + 3) / 4;   // 4 waves (nodes) per 256-thread block
    gather1_k<<<gb, 256, 0, stream>>>(xws1, dinv, rowp, csr, b1, h1);

    gemm_scaled_k<hf><<<ggrid, 256, 0, stream>>>(h1, W2, dinv, xws2, N_NODES);

    gather2_pool_k<<<gb, 256, 0, stream>>>(xws2, dinv, rowp, csr, b2, batch, Wfc,
                                           pool, cnt);

    finalize_k<<<2, 256, 0, stream>>>(pool, cnt, bfc, out);
}

// Round 5
// 363.260 us; speedup vs baseline: 1.4009x; 1.1975x over previous
//
#include <hip/hip_runtime.h>
#include <hip/hip_bf16.h>

typedef float f2 __attribute__((ext_vector_type(2)));
typedef float f4 __attribute__((ext_vector_type(4)));
typedef _Float16 hf;
typedef hf hf2 __attribute__((ext_vector_type(2)));
typedef hf hf4 __attribute__((ext_vector_type(4)));

#define N_NODES 50000
#define N_EDGES 800000
#define CH 128
#define N_GRAPHS 512

// ---------------- degree histogram ----------------
__global__ __launch_bounds__(256) void deg_hist_k(const int* __restrict__ dst,
                                                  int* __restrict__ deg) {
    int e = blockIdx.x * 256 + threadIdx.x;
    if (e < N_EDGES) atomicAdd(&deg[dst[e]], 1);
}

// ---------------- 3-step exclusive scan over 50000 ints ----------------
__global__ __launch_bounds__(1024) void scan1_k(const int* __restrict__ deg,
                                                int* __restrict__ tmp,
                                                int* __restrict__ bsum, int n) {
    __shared__ int s[1024];
    int tid = threadIdx.x;
    int gid = blockIdx.x * 1024 + tid;
    int v = (gid < n) ? deg[gid] : 0;
    s[tid] = v;
    __syncthreads();
    for (int off = 1; off < 1024; off <<= 1) {
        int t = (tid >= off) ? s[tid - off] : 0;
        __syncthreads();
        s[tid] += t;
        __syncthreads();
    }
    if (gid < n) tmp[gid] = s[tid];
    if (tid == 1023) bsum[blockIdx.x] = s[tid];
}

__global__ void scan2_k(int* __restrict__ bsum, int nb) {
    int lane = threadIdx.x;  // one wave of 64
    int v = (lane < nb) ? bsum[lane] : 0;
    for (int off = 1; off < 64; off <<= 1) {
        int t = __shfl_up(v, off);
        if (lane >= off) v += t;
    }
    if (lane < nb) bsum[lane] = v;
}

// writes row_ptr (exclusive), cursor copy, and dinv = rsqrt(deg+1)
__global__ __launch_bounds__(1024) void scan3_k(const int* __restrict__ tmp,
                                                const int* __restrict__ bsum,
                                                const int* __restrict__ deg,
                                                int* __restrict__ rowp,
                                                int* __restrict__ cursor,
                                                float* __restrict__ dinv, int n) {
    int gid = blockIdx.x * 1024 + threadIdx.x;
    if (gid >= n) return;
    int off = blockIdx.x ? bsum[blockIdx.x - 1] : 0;
    int incl = tmp[gid] + off;
    rowp[gid + 1] = incl;
    cursor[gid] = incl - deg[gid];
    dinv[gid] = rsqrtf((float)deg[gid] + 1.0f);  // +1 for self-loop
    if (gid == 0) rowp[0] = 0;
}

// ---------------- CSR fill (src ids bucketed by dst) ----------------
__global__ __launch_bounds__(256) void csr_fill_k(const int* __restrict__ src,
                                                  const int* __restrict__ dst,
                                                  int* __restrict__ cursor,
                                                  int* __restrict__ csr) {
    int e = blockIdx.x * 256 + threadIdx.x;
    if (e < N_EDGES) {
        int d = dst[e];
        int pos = atomicAdd(&cursor[d], 1);
        csr[pos] = src[e];
    }
}

// ------- GEMM: out[M,128] = (A[M,128] @ W[128,128]) * dinv[row], fp16 out ----
template <typename TA>
__global__ __launch_bounds__(256) void gemm_scaled_k(const TA* __restrict__ A,
                                                     const float* __restrict__ W,
                                                     const float* __restrict__ dinv,
                                                     hf* __restrict__ out, int M) {
    __shared__ float sA[64][132];   // padded
    __shared__ float sW[128][68];
    int tid = threadIdx.x;
    int row0 = blockIdx.x * 64;
    int col0 = blockIdx.y * 64;

    #pragma unroll
    for (int rep = 0; rep < 8; ++rep) {
        int idx = rep * 256 + tid;       // 0..2047, 4 ch each
        int r = idx >> 5, k4 = idx & 31;
        f4 vf = {0.f, 0.f, 0.f, 0.f};
        int row = row0 + r;
        if (row < M) {
            if constexpr (sizeof(TA) == 4) {
                vf = *(const f4*)&A[row * 128 + k4 * 4];
            } else {
                hf4 v = *(const hf4*)&A[row * 128 + k4 * 4];
                vf = f4{(float)v[0], (float)v[1], (float)v[2], (float)v[3]};
            }
        }
        *(f4*)&sA[r][k4 * 4] = vf;
    }
    #pragma unroll
    for (int rep = 0; rep < 8; ++rep) {
        int idx = rep * 256 + tid;       // 0..2047
        int k = idx >> 4, c4 = idx & 15;
        f4 v = *(const f4*)&W[k * 128 + col0 + c4 * 4];
        *(f4*)&sW[k][c4 * 4] = v;
    }
    __syncthreads();

    int tx = tid & 15, ty = tid >> 4;
    float acc[4][4] = {};
    for (int k = 0; k < 128; k += 4) {
        f4 a[4], b[4];
        #pragma unroll
        for (int i = 0; i < 4; ++i) a[i] = *(const f4*)&sA[ty * 4 + i][k];
        #pragma unroll
        for (int kk = 0; kk < 4; ++kk) b[kk] = *(const f4*)&sW[k + kk][tx * 4];
        #pragma unroll
        for (int i = 0; i < 4; ++i)
            #pragma unroll
            for (int j = 0; j < 4; ++j)
                acc[i][j] += a[i][0] * b[0][j] + a[i][1] * b[1][j] +
                             a[i][2] * b[2][j] + a[i][3] * b[3][j];
    }
    #pragma unroll
    for (int i = 0; i < 4; ++i) {
        int row = row0 + ty * 4 + i;
        if (row < M) {
            float dv = dinv[row];
            hf4 o = {(hf)(acc[i][0] * dv), (hf)(acc[i][1] * dv),
                     (hf)(acc[i][2] * dv), (hf)(acc[i][3] * dv)};
            *(hf4*)&out[row * 128 + col0 + tx * 4] = o;
        }
    }
}

// ---------------- half-wave gather core ----------------
// 32 lanes own one node; row = 256B = 32 x hf4. Edge ids (self + up to 31
// edges) prefetched in ONE coalesced load, broadcast via shfl. Payload loads
// issued in explicit 8-deep batches into named registers so 8 loads stay in
// flight per half-wave (16 per wave). deg>31 handled by a uniform tail loop.
#define ACC4(v) do { acc[0] += (float)(v)[0]; acc[1] += (float)(v)[1]; \
                     acc[2] += (float)(v)[2]; acc[3] += (float)(v)[3]; } while (0)

__device__ __forceinline__ f4 gather_half(const hf4* __restrict__ rows,
                                          const int* __restrict__ rowp,
                                          const int* __restrict__ csr,
                                          int node, int lane) {
    int hl = lane & 31;          // hf4 slot within 256B row
    int hbase = lane & 32;       // 0 or 32: shfl base of this half
    int beg = rowp[node], end = rowp[node + 1];
    int cnt = end - beg + 1;     // + self
    int myE = node;              // slot 0 = self-loop
    if (hl > 0) {
        int j = beg + hl - 1;
        if (j < end) myE = csr[j];
    }
    f4 acc = {0.f, 0.f, 0.f, 0.f};
    int pre = cnt < 32 ? cnt : 32;
    int e = 0;
    for (; e + 8 <= pre; e += 8) {
        int s0 = __shfl(myE, hbase + e + 0);
        int s1 = __shfl(myE, hbase + e + 1);
        int s2 = __shfl(myE, hbase + e + 2);
        int s3 = __shfl(myE, hbase + e + 3);
        int s4 = __shfl(myE, hbase + e + 4);
        int s5 = __shfl(myE, hbase + e + 5);
        int s6 = __shfl(myE, hbase + e + 6);
        int s7 = __shfl(myE, hbase + e + 7);
        hf4 v0 = rows[s0 * 32 + hl];
        hf4 v1 = rows[s1 * 32 + hl];
        hf4 v2 = rows[s2 * 32 + hl];
        hf4 v3 = rows[s3 * 32 + hl];
        hf4 v4 = rows[s4 * 32 + hl];
        hf4 v5 = rows[s5 * 32 + hl];
        hf4 v6 = rows[s6 * 32 + hl];
        hf4 v7 = rows[s7 * 32 + hl];
        ACC4(v0); ACC4(v1); ACC4(v2); ACC4(v3);
        ACC4(v4); ACC4(v5); ACC4(v6); ACC4(v7);
    }
    if (e + 4 <= pre) {
        int s0 = __shfl(myE, hbase + e + 0);
        int s1 = __shfl(myE, hbase + e + 1);
        int s2 = __shfl(myE, hbase + e + 2);
        int s3 = __shfl(myE, hbase + e + 3);
        hf4 v0 = rows[s0 * 32 + hl];
        hf4 v1 = rows[s1 * 32 + hl];
        hf4 v2 = rows[s2 * 32 + hl];
        hf4 v3 = rows[s3 * 32 + hl];
        ACC4(v0); ACC4(v1); ACC4(v2); ACC4(v3);
        e += 4;
    }
    for (; e < pre; ++e) {
        int s0 = __shfl(myE, hbase + e);
        hf4 v0 = rows[s0 * 32 + hl];
        ACC4(v0);
    }
    // overflow tail (deg > 31): uniform loads
    for (int j = beg + 31; j < end; ++j) {
        int s = csr[j];
        hf4 v = rows[s * 32 + hl];
        ACC4(v);
    }
    return acc;
}

// ---------------- layer-1 aggregate: half-wave per node ----------------
__global__ __launch_bounds__(256) void gather1_k(const hf* __restrict__ xws,
                                                 const float* __restrict__ dinv,
                                                 const int* __restrict__ rowp,
                                                 const int* __restrict__ csr,
                                                 const float* __restrict__ bias,
                                                 hf* __restrict__ h) {
    int node = blockIdx.x * 8 + (threadIdx.x >> 5);
    if (node >= N_NODES) return;
    int lane = threadIdx.x & 63;
    int hl = lane & 31;
    f4 acc = gather_half((const hf4*)xws, rowp, csr, node, lane);
    float dn = dinv[node];
    f4 bb = *(const f4*)&bias[hl * 4];
    hf4 o;
    #pragma unroll
    for (int k = 0; k < 4; ++k)
        o[k] = (hf)fmaxf(acc[k] * dn + bb[k], 0.f);
    ((hf4*)h)[node * 32 + hl] = o;
}

// ------- layer-2 aggregate fused with mean-pool dot(Wfc) -------
__global__ __launch_bounds__(256) void gather2_pool_k(const hf* __restrict__ xws,
                                                      const float* __restrict__ dinv,
                                                      const int* __restrict__ rowp,
                                                      const int* __restrict__ csr,
                                                      const float* __restrict__ bias,
                                                      const int* __restrict__ batch,
                                                      const float* __restrict__ Wfc,
                                                      float* __restrict__ pool,
                                                      float* __restrict__ cnt) {
    int node = blockIdx.x * 8 + (threadIdx.x >> 5);
    if (node >= N_NODES) return;
    int lane = threadIdx.x & 63;
    int hl = lane & 31;
    f4 acc = gather_half((const hf4*)xws, rowp, csr, node, lane);
    float dn = dinv[node];
    f4 bb = *(const f4*)&bias[hl * 4];
    f4 wf = *(const f4*)&Wfc[hl * 4];
    float p = 0.f;
    #pragma unroll
    for (int k = 0; k < 4; ++k)
        p += fmaxf(acc[k] * dn + bb[k], 0.f) * wf[k];
    // reduce within the 32-lane half (xor offsets stay inside the half)
    #pragma unroll
    for (int off = 16; off > 0; off >>= 1) p += __shfl_xor(p, off);
    if (hl == 0) {
        int g = batch[node];
        atomicAdd(&pool[g], p);
        atomicAdd(&cnt[g], 1.0f);
    }
}

__global__ void finalize_k(const float* __restrict__ pool,
                           const float* __restrict__ cnt,
                           const float* __restrict__ bfc,
                           float* __restrict__ out) {
    int g = blockIdx.x * blockDim.x + threadIdx.x;
    if (g < N_GRAPHS) out[g] = pool[g] / fmaxf(cnt[g], 1.0f) + bfc[0];
}

extern "C" void kernel_launch(void* const* d_in, const int* in_sizes, int n_in,
                              void* d_out, int out_size, void* d_ws, size_t ws_size,
                              hipStream_t stream) {
    const float* x    = (const float*)d_in[0];
    const int*   ei   = (const int*)d_in[1];   // [2, E] flat, int32
    const int*   batch= (const int*)d_in[2];
    const float* W1   = (const float*)d_in[3];
    const float* b1   = (const float*)d_in[4];
    const float* W2   = (const float*)d_in[5];
    const float* b2   = (const float*)d_in[6];
    const float* Wfc  = (const float*)d_in[7];
    const float* bfc  = (const float*)d_in[8];
    float* out = (float*)d_out;

    const int* src = ei;
    const int* dst = ei + N_EDGES;

    // workspace carve-up (every segment a multiple of 256B so xws rows are
    // cache-line aligned: each fp16 row = exactly two 128B lines)
    char* w = (char*)d_ws;
    float* dinv   = (float*)w; w += 50048 * 4;
    int*   deg    = (int*)w;   w += 50048 * 4;
    int*   rowp   = (int*)w;   w += 50176 * 4;   // 50001 used, padded
    int*   cursor = (int*)w;   w += 50048 * 4;
    int*   stmp   = (int*)w;   w += 50048 * 4;
    int*   bsum   = (int*)w;   w += 256 * 4;
    int*   csr    = (int*)w;   w += N_EDGES * 4;
    hf*    xws1   = (hf*)w;    w += (size_t)N_NODES * 128 * 2;
    hf*    h1     = (hf*)w;    w += (size_t)N_NODES * 128 * 2;
    hf*    xws2   = (hf*)w;    w += (size_t)N_NODES * 128 * 2;
    float* pool   = (float*)w; w += 512 * 4;
    float* cnt    = (float*)w; w += 512 * 4;

    hipMemsetAsync(deg, 0, N_NODES * sizeof(int), stream);
    hipMemsetAsync(pool, 0, 2 * 512 * sizeof(float), stream);  // pool + cnt

    int eb = (N_EDGES + 255) / 256;
    deg_hist_k<<<eb, 256, 0, stream>>>(dst, deg);

    int nb = (N_NODES + 1023) / 1024;   // 49
    scan1_k<<<nb, 1024, 0, stream>>>(deg, stmp, bsum, N_NODES);
    scan2_k<<<1, 64, 0, stream>>>(bsum, nb);
    scan3_k<<<nb, 1024, 0, stream>>>(stmp, bsum, deg, rowp, cursor, dinv, N_NODES);

    csr_fill_k<<<eb, 256, 0, stream>>>(src, dst, cursor, csr);

    dim3 ggrid((N_NODES + 63) / 64, 2);
    gemm_scaled_k<float><<<ggrid, 256, 0, stream>>>(x, W1, dinv, xws1, N_NODES);

    int gb = (N_NODES + 7) / 8;   // 8 half-waves (nodes) per 256-thread block
    gather1_k<<<gb, 256, 0, stream>>>(xws1, dinv, rowp, csr, b1, h1);

    gemm_scaled_k<hf><<<ggrid, 256, 0, stream>>>(h1, W2, dinv, xws2, N_NODES);

    gather2_pool_k<<<gb, 256, 0, stream>>>(xws2, dinv, rowp, csr, b2, batch, Wfc,
                                           pool, cnt);

    finalize_k<<<2, 256, 0, stream>>>(pool, cnt, bfc, out);
}